// Round 3
// baseline (754.309 us; speedup 1.0000x reference)
//
#include <hip/hip_runtime.h>

#define N_NODES   100352
#define N_EDGES   1605632
#define IN_C      128
#define HID_C     64
#define OUT_C     32
#define NUM_GRAPHS 512
#define NPG       196
#define TOPK      30

// ws layout (bytes)
#define OFF_DEG     0u          // int[N]
#define OFF_ROWPTR  401408u     // int[N]
#define OFF_FILL    802816u     // int[N]
#define OFF_BSUM    1204224u    // int[98]
#define OFF_BOFF    1204736u    // int[98]
#define OFF_DIS     1205248u    // float[N]
#define OFF_CSR     1606656u    // int[E]
#define OFF_XW1     8029184u    // float[N*64]  (dis-scaled)
#define OFF_H       33719296u   // float[N*64]
#define OFF_XW2     59409408u   // float[N*32]  (dis-scaled)
#define OFF_OUT2    72254464u   // float[N*32]
// total: ~85 MB

__global__ void k_deg(const int* __restrict__ dst, int* __restrict__ deg) {
    int i = blockIdx.x * blockDim.x + threadIdx.x;
    if (i < N_EDGES) atomicAdd(&deg[dst[i]], 1);
}

__global__ __launch_bounds__(1024) void k_bsum(const int* __restrict__ deg, int* __restrict__ bsum) {
    __shared__ int s[1024];
    int t = threadIdx.x;
    s[t] = deg[blockIdx.x * 1024 + t];
    __syncthreads();
    for (int o = 512; o > 0; o >>= 1) {
        if (t < o) s[t] += s[t + o];
        __syncthreads();
    }
    if (t == 0) bsum[blockIdx.x] = s[0];
}

__global__ void k_bscan(const int* __restrict__ bsum, int* __restrict__ boff) {
    if (threadIdx.x == 0) {
        int run = 0;
        for (int b = 0; b < 98; ++b) { boff[b] = run; run += bsum[b]; }
    }
}

__global__ __launch_bounds__(1024) void k_scan(const int* __restrict__ deg, const int* __restrict__ boff,
                                               int* __restrict__ row_ptr, int* __restrict__ fill_pos,
                                               float* __restrict__ dis) {
    __shared__ int s[1024];
    int t = threadIdx.x;
    int i = blockIdx.x * 1024 + t;
    int v = deg[i];
    s[t] = v;
    __syncthreads();
    for (int o = 1; o < 1024; o <<= 1) {
        int a = (t >= o) ? s[t - o] : 0;
        __syncthreads();
        s[t] += a;
        __syncthreads();
    }
    int start = boff[blockIdx.x] + s[t] - v;   // exclusive prefix
    row_ptr[i] = start;
    fill_pos[i] = start;
    dis[i] = (float)(1.0 / sqrt((double)(v + 1)));   // +1 self-loop
}

__global__ void k_fill(const int* __restrict__ src, const int* __restrict__ dst,
                       int* __restrict__ fill_pos, int* __restrict__ csr_src) {
    int i = blockIdx.x * blockDim.x + threadIdx.x;
    if (i < N_EDGES) {
        int d = dst[i];
        int p = atomicAdd(&fill_pos[d], 1);
        csr_src[p] = src[i];
    }
}

// xw1s = dis[n] * (x @ W1). W1 column in VGPRs; 4 nodes in flight per thread (ILP).
#define MM1_NPW 8
__global__ __launch_bounds__(256) void k_mm1(const float* __restrict__ x, const float* __restrict__ W1,
                                             const float* __restrict__ dis, float* __restrict__ xw1s) {
    int lane = threadIdx.x & 63;
    int wid = blockIdx.x * 4 + (threadIdx.x >> 6);
    float w[IN_C];
#pragma unroll
    for (int k = 0; k < IN_C; ++k)
        w[k] = W1[k * HID_C + lane];                 // coalesced across lanes
    int n0 = wid * MM1_NPW;
    for (int g = 0; g < MM1_NPW; g += 4) {
        int n = n0 + g;
        const float4* xr0 = (const float4*)(x + (size_t)(n + 0) * IN_C);
        const float4* xr1 = (const float4*)(x + (size_t)(n + 1) * IN_C);
        const float4* xr2 = (const float4*)(x + (size_t)(n + 2) * IN_C);
        const float4* xr3 = (const float4*)(x + (size_t)(n + 3) * IN_C);
        float a0 = 0.f, a1 = 0.f, a2 = 0.f, a3 = 0.f;
#pragma unroll 4
        for (int q = 0; q < IN_C / 4; ++q) {
            float4 v0 = xr0[q], v1 = xr1[q], v2 = xr2[q], v3 = xr3[q];
            a0 = fmaf(v0.x, w[4 * q + 0], a0); a0 = fmaf(v0.y, w[4 * q + 1], a0);
            a0 = fmaf(v0.z, w[4 * q + 2], a0); a0 = fmaf(v0.w, w[4 * q + 3], a0);
            a1 = fmaf(v1.x, w[4 * q + 0], a1); a1 = fmaf(v1.y, w[4 * q + 1], a1);
            a1 = fmaf(v1.z, w[4 * q + 2], a1); a1 = fmaf(v1.w, w[4 * q + 3], a1);
            a2 = fmaf(v2.x, w[4 * q + 0], a2); a2 = fmaf(v2.y, w[4 * q + 1], a2);
            a2 = fmaf(v2.z, w[4 * q + 2], a2); a2 = fmaf(v2.w, w[4 * q + 3], a2);
            a3 = fmaf(v3.x, w[4 * q + 0], a3); a3 = fmaf(v3.y, w[4 * q + 1], a3);
            a3 = fmaf(v3.z, w[4 * q + 2], a3); a3 = fmaf(v3.w, w[4 * q + 3], a3);
        }
        xw1s[(size_t)(n + 0) * HID_C + lane] = a0 * dis[n + 0];
        xw1s[(size_t)(n + 1) * HID_C + lane] = a1 * dis[n + 1];
        xw1s[(size_t)(n + 2) * HID_C + lane] = a2 * dis[n + 2];
        xw1s[(size_t)(n + 3) * HID_C + lane] = a3 * dis[n + 3];
    }
}

// layer-1 aggregation: one 64-lane wave per node; dis folded, inner = shfl+load+add.
__global__ __launch_bounds__(256) void k_agg1(const float* __restrict__ xw1s, const int* __restrict__ csr_src,
                                              const int* __restrict__ row_ptr, const int* __restrict__ deg,
                                              const float* __restrict__ dis, const float* __restrict__ b1,
                                              float* __restrict__ h) {
    int lane = threadIdx.x & 63;
    int v = blockIdx.x * 4 + (threadIdx.x >> 6);
    int start = row_ptr[v];
    int cnt = deg[v];
    float acc = xw1s[(size_t)v * HID_C + lane];   // self-loop term (already dis-scaled)
    for (int base = 0; base < cnt; base += 64) {
        int mcnt = min(64, cnt - base);
        int sj = 0;
        if (lane < mcnt) sj = csr_src[start + base + lane];
        for (int j = 0; j < mcnt; ++j) {
            int s = __shfl(sj, j);
            acc += xw1s[(size_t)s * HID_C + lane];
        }
    }
    float o = fmaf(dis[v], acc, b1[lane]);
    h[(size_t)v * HID_C + lane] = fmaxf(o, 0.f);   // ReLU fused
}

// xw2s = dis[n] * (h @ W2). Half-wave = node; 4 accs per thread (8 nodes/wave iter).
#define MM2_NPW 8
__global__ __launch_bounds__(256) void k_mm2(const float* __restrict__ h, const float* __restrict__ W2,
                                             const float* __restrict__ dis, float* __restrict__ xw2s) {
    int lane = threadIdx.x & 63;
    int c = lane & 31;
    int half = lane >> 5;
    int wid = blockIdx.x * 4 + (threadIdx.x >> 6);
    float w[HID_C];
#pragma unroll
    for (int k = 0; k < HID_C; ++k)
        w[k] = W2[k * OUT_C + c];
    int m0 = wid * MM2_NPW;
    int nA = m0 + 0 + half, nB = m0 + 2 + half, nC = m0 + 4 + half, nD = m0 + 6 + half;
    const float4* hA = (const float4*)(h + (size_t)nA * HID_C);
    const float4* hB = (const float4*)(h + (size_t)nB * HID_C);
    const float4* hC = (const float4*)(h + (size_t)nC * HID_C);
    const float4* hD = (const float4*)(h + (size_t)nD * HID_C);
    float a0 = 0.f, a1 = 0.f, a2 = 0.f, a3 = 0.f;
#pragma unroll 4
    for (int q = 0; q < HID_C / 4; ++q) {
        float4 v0 = hA[q], v1 = hB[q], v2 = hC[q], v3 = hD[q];
        a0 = fmaf(v0.x, w[4 * q + 0], a0); a0 = fmaf(v0.y, w[4 * q + 1], a0);
        a0 = fmaf(v0.z, w[4 * q + 2], a0); a0 = fmaf(v0.w, w[4 * q + 3], a0);
        a1 = fmaf(v1.x, w[4 * q + 0], a1); a1 = fmaf(v1.y, w[4 * q + 1], a1);
        a1 = fmaf(v1.z, w[4 * q + 2], a1); a1 = fmaf(v1.w, w[4 * q + 3], a1);
        a2 = fmaf(v2.x, w[4 * q + 0], a2); a2 = fmaf(v2.y, w[4 * q + 1], a2);
        a2 = fmaf(v2.z, w[4 * q + 2], a2); a2 = fmaf(v2.w, w[4 * q + 3], a2);
        a3 = fmaf(v3.x, w[4 * q + 0], a3); a3 = fmaf(v3.y, w[4 * q + 1], a3);
        a3 = fmaf(v3.z, w[4 * q + 2], a3); a3 = fmaf(v3.w, w[4 * q + 3], a3);
    }
    xw2s[(size_t)nA * OUT_C + c] = a0 * dis[nA];
    xw2s[(size_t)nB * OUT_C + c] = a1 * dis[nB];
    xw2s[(size_t)nC * OUT_C + c] = a2 * dis[nC];
    xw2s[(size_t)nD * OUT_C + c] = a3 * dis[nD];
}

// layer-2 aggregation: 32-lane group per node; dis folded.
__global__ __launch_bounds__(256) void k_agg2(const float* __restrict__ xw2s, const int* __restrict__ csr_src,
                                              const int* __restrict__ row_ptr, const int* __restrict__ deg,
                                              const float* __restrict__ dis, const float* __restrict__ b2,
                                              float* __restrict__ out2) {
    int lane = threadIdx.x & 31;
    int v = blockIdx.x * 8 + (threadIdx.x >> 5);
    int start = row_ptr[v];
    int cnt = deg[v];
    float acc = xw2s[(size_t)v * OUT_C + lane];   // self-loop term
    for (int base = 0; base < cnt; base += 32) {
        int mcnt = min(32, cnt - base);
        int sj = 0;
        if (lane < mcnt) sj = csr_src[start + base + lane];
        for (int j = 0; j < mcnt; ++j) {
            int s = __shfl(sj, j, 32);
            acc += xw2s[(size_t)s * OUT_C + lane];
        }
    }
    out2[(size_t)v * OUT_C + lane] = fmaf(dis[v], acc, b2[lane]);
}

// per-graph top-30 by channel 31 (desc, stable), emit [512, 30*32] f32.
__global__ __launch_bounds__(256) void k_sort(const float* __restrict__ out2, float* __restrict__ out) {
    __shared__ float keys[NPG];
    __shared__ int order[TOPK];
    int g = blockIdx.x;
    int tid = threadIdx.x;
    int base = g * NPG;
    if (tid < NPG) keys[tid] = out2[(size_t)(base + tid) * OUT_C + (OUT_C - 1)];
    __syncthreads();
    if (tid < NPG) {
        float my = keys[tid];
        int r = 0;
        for (int j = 0; j < NPG; ++j) {
            float kj = keys[j];
            r += (kj > my) || (kj == my && j < tid);
        }
        if (r < TOPK) order[r] = tid;
    }
    __syncthreads();
    for (int idx = tid; idx < TOPK * OUT_C; idx += 256) {
        int r = idx >> 5;
        int c = idx & 31;
        int n = order[r];
        out[g * (TOPK * OUT_C) + idx] = out2[(size_t)(base + n) * OUT_C + c];
    }
}

extern "C" void kernel_launch(void* const* d_in, const int* in_sizes, int n_in,
                              void* d_out, int out_size, void* d_ws, size_t ws_size,
                              hipStream_t stream) {
    const float* x  = (const float*)d_in[0];
    const int*   ei = (const int*)d_in[1];
    const int*   srcp = ei;             // edge_index[0]
    const int*   dstp = ei + N_EDGES;   // edge_index[1]
    // d_in[2] (batch) unused: graphs are contiguous 196-node blocks.
    const float* W1 = (const float*)d_in[3];
    const float* b1 = (const float*)d_in[4];
    const float* W2 = (const float*)d_in[5];
    const float* b2 = (const float*)d_in[6];
    float* out = (float*)d_out;

    char* w = (char*)d_ws;
    int*    deg      = (int*)(w + OFF_DEG);
    int*    row_ptr  = (int*)(w + OFF_ROWPTR);
    int*    fill_pos = (int*)(w + OFF_FILL);
    int*    bsum     = (int*)(w + OFF_BSUM);
    int*    boff     = (int*)(w + OFF_BOFF);
    float*  dis      = (float*)(w + OFF_DIS);
    int*    csr_src  = (int*)(w + OFF_CSR);
    float*  xw1s     = (float*)(w + OFF_XW1);
    float*  h        = (float*)(w + OFF_H);
    float*  xw2s     = (float*)(w + OFF_XW2);
    float*  out2     = (float*)(w + OFF_OUT2);

    hipMemsetAsync(deg, 0, N_NODES * sizeof(int), stream);
    k_deg  <<<(N_EDGES + 255) / 256, 256, 0, stream>>>(dstp, deg);
    k_bsum <<<98, 1024, 0, stream>>>(deg, bsum);
    k_bscan<<<1, 64, 0, stream>>>(bsum, boff);
    k_scan <<<98, 1024, 0, stream>>>(deg, boff, row_ptr, fill_pos, dis);
    k_fill <<<(N_EDGES + 255) / 256, 256, 0, stream>>>(srcp, dstp, fill_pos, csr_src);
    k_mm1  <<<N_NODES / (MM1_NPW * 4), 256, 0, stream>>>(x, W1, dis, xw1s);
    k_agg1 <<<N_NODES / 4, 256, 0, stream>>>(xw1s, csr_src, row_ptr, deg, dis, b1, h);
    k_mm2  <<<N_NODES / (MM2_NPW * 4), 256, 0, stream>>>(h, W2, dis, xw2s);
    k_agg2 <<<N_NODES / 8, 256, 0, stream>>>(xw2s, csr_src, row_ptr, deg, dis, b2, out2);
    k_sort <<<NUM_GRAPHS, 256, 0, stream>>>(out2, out);
}

// Round 4
// 448.167 us; speedup vs baseline: 1.6831x; 1.6831x over previous
//
#include <hip/hip_runtime.h>

#define N_NODES   100352
#define N_EDGES   1605632
#define IN_C      128
#define HID_C     64
#define OUT_C     32
#define NUM_GRAPHS 512
#define NPG       196
#define TOPK      30

// ws layout (bytes)
#define OFF_DEG     0u          // int[N]
#define OFF_ROWPTR  401408u     // int[N]
#define OFF_FILL    802816u     // int[N]
#define OFF_BSUM    1204224u    // int[98]
#define OFF_BOFF    1204736u    // int[98]
#define OFF_DIS     1205248u    // float[N]
#define OFF_CSR     1606656u    // int[E]
#define OFF_XW1     8029184u    // float[N*64]  (dis-scaled)
#define OFF_H       33719296u   // float[N*64]
#define OFF_XW2     59409408u   // float[N*32]  (dis-scaled)
#define OFF_OUT2    72254464u   // float[N*32]
// total: ~85 MB

__global__ void k_deg(const int* __restrict__ dst, int* __restrict__ deg) {
    int i = blockIdx.x * blockDim.x + threadIdx.x;
    if (i < N_EDGES) atomicAdd(&deg[dst[i]], 1);
}

__global__ __launch_bounds__(1024) void k_bsum(const int* __restrict__ deg, int* __restrict__ bsum) {
    __shared__ int s[1024];
    int t = threadIdx.x;
    s[t] = deg[blockIdx.x * 1024 + t];
    __syncthreads();
    for (int o = 512; o > 0; o >>= 1) {
        if (t < o) s[t] += s[t + o];
        __syncthreads();
    }
    if (t == 0) bsum[blockIdx.x] = s[0];
}

__global__ void k_bscan(const int* __restrict__ bsum, int* __restrict__ boff) {
    if (threadIdx.x == 0) {
        int run = 0;
        for (int b = 0; b < 98; ++b) { boff[b] = run; run += bsum[b]; }
    }
}

__global__ __launch_bounds__(1024) void k_scan(const int* __restrict__ deg, const int* __restrict__ boff,
                                               int* __restrict__ row_ptr, int* __restrict__ fill_pos,
                                               float* __restrict__ dis) {
    __shared__ int s[1024];
    int t = threadIdx.x;
    int i = blockIdx.x * 1024 + t;
    int v = deg[i];
    s[t] = v;
    __syncthreads();
    for (int o = 1; o < 1024; o <<= 1) {
        int a = (t >= o) ? s[t - o] : 0;
        __syncthreads();
        s[t] += a;
        __syncthreads();
    }
    int start = boff[blockIdx.x] + s[t] - v;   // exclusive prefix
    row_ptr[i] = start;
    fill_pos[i] = start;
    dis[i] = (float)(1.0 / sqrt((double)(v + 1)));   // +1 self-loop
}

__global__ void k_fill(const int* __restrict__ src, const int* __restrict__ dst,
                       int* __restrict__ fill_pos, int* __restrict__ csr_src) {
    int i = blockIdx.x * blockDim.x + threadIdx.x;
    if (i < N_EDGES) {
        int d = dst[i];
        int p = atomicAdd(&fill_pos[d], 1);
        csr_src[p] = src[i];
    }
}

// xw1s = dis[n] * (x @ W1). W1 in LDS; lane = col; 8 nodes in flight per thread.
// All register arrays (acc, xv) indexed only by fully-unrolled static loops (rule #20).
#define MM1_NPW 8
__global__ __launch_bounds__(256) void k_mm1(const float* __restrict__ x, const float* __restrict__ W1,
                                             const float* __restrict__ dis, float* __restrict__ xw1s) {
    __shared__ float wlds[IN_C * HID_C];   // 32 KB
    int tid = threadIdx.x;
    for (int i = tid; i < IN_C * HID_C / 4; i += 256)
        ((float4*)wlds)[i] = ((const float4*)W1)[i];
    __syncthreads();
    int lane = tid & 63;
    int wid = blockIdx.x * 4 + (tid >> 6);
    int n0 = wid * MM1_NPW;
    const float* xb = x + (size_t)n0 * IN_C;
    float acc[MM1_NPW] = {0.f, 0.f, 0.f, 0.f, 0.f, 0.f, 0.f, 0.f};
#pragma unroll 4
    for (int q = 0; q < IN_C / 4; ++q) {
        float4 xv[MM1_NPW];
#pragma unroll
        for (int j = 0; j < MM1_NPW; ++j)
            xv[j] = *(const float4*)(xb + j * IN_C + 4 * q);   // wave-uniform -> broadcast
#pragma unroll
        for (int kk = 0; kk < 4; ++kk) {
            float wv = wlds[(4 * q + kk) * HID_C + lane];       // LDS: runtime index is fine
#pragma unroll
            for (int j = 0; j < MM1_NPW; ++j) {
                float xs = (kk == 0) ? xv[j].x : (kk == 1) ? xv[j].y : (kk == 2) ? xv[j].z : xv[j].w;
                acc[j] = fmaf(xs, wv, acc[j]);
            }
        }
    }
#pragma unroll
    for (int j = 0; j < MM1_NPW; ++j)
        xw1s[(size_t)(n0 + j) * HID_C + lane] = acc[j] * dis[n0 + j];
}

// layer-1 aggregation: one 64-lane wave per node; dis folded; 4 gather loads in flight.
__global__ __launch_bounds__(256) void k_agg1(const float* __restrict__ xw1s, const int* __restrict__ csr_src,
                                              const int* __restrict__ row_ptr, const int* __restrict__ deg,
                                              const float* __restrict__ dis, const float* __restrict__ b1,
                                              float* __restrict__ h) {
    int lane = threadIdx.x & 63;
    int v = blockIdx.x * 4 + (threadIdx.x >> 6);
    int start = row_ptr[v];
    int cnt = deg[v];
    float acc0 = xw1s[(size_t)v * HID_C + lane];   // self-loop term (already dis-scaled)
    float acc1 = 0.f;
    for (int base = 0; base < cnt; base += 64) {
        int mcnt = min(64, cnt - base);
        int sj = 0;
        if (lane < mcnt) sj = csr_src[start + base + lane];
        int j = 0;
        for (; j + 4 <= mcnt; j += 4) {
            int s0 = __shfl(sj, j + 0), s1 = __shfl(sj, j + 1);
            int s2 = __shfl(sj, j + 2), s3 = __shfl(sj, j + 3);
            float v0 = xw1s[(size_t)s0 * HID_C + lane];
            float v1 = xw1s[(size_t)s1 * HID_C + lane];
            float v2 = xw1s[(size_t)s2 * HID_C + lane];
            float v3 = xw1s[(size_t)s3 * HID_C + lane];
            acc0 += v0 + v2;
            acc1 += v1 + v3;
        }
        for (; j < mcnt; ++j) {
            int s = __shfl(sj, j);
            acc0 += xw1s[(size_t)s * HID_C + lane];
        }
    }
    float o = fmaf(dis[v], acc0 + acc1, b1[lane]);
    h[(size_t)v * HID_C + lane] = fmaxf(o, 0.f);   // ReLU fused
}

// xw2s = dis[n] * (h @ W2). W2 in LDS; half-wave = node slot; 8 nodes per half-wave.
#define MM2_NPW 8
__global__ __launch_bounds__(256) void k_mm2(const float* __restrict__ h, const float* __restrict__ W2,
                                             const float* __restrict__ dis, float* __restrict__ xw2s) {
    __shared__ float wlds[HID_C * OUT_C];   // 8 KB
    int tid = threadIdx.x;
    for (int i = tid; i < HID_C * OUT_C / 4; i += 256)
        ((float4*)wlds)[i] = ((const float4*)W2)[i];
    __syncthreads();
    int lane = tid & 63;
    int c = lane & 31;
    int half = lane >> 5;
    int wid = blockIdx.x * 4 + (tid >> 6);
    int n0 = wid * 2 * MM2_NPW;             // 16 nodes per wave
    const float* hb = h + (size_t)(n0 + half) * HID_C;
    float acc[MM2_NPW] = {0.f, 0.f, 0.f, 0.f, 0.f, 0.f, 0.f, 0.f};
#pragma unroll 4
    for (int q = 0; q < HID_C / 4; ++q) {
        float4 xv[MM2_NPW];
#pragma unroll
        for (int j = 0; j < MM2_NPW; ++j)
            xv[j] = *(const float4*)(hb + (size_t)(2 * j) * HID_C + 4 * q);
#pragma unroll
        for (int kk = 0; kk < 4; ++kk) {
            float wv = wlds[(4 * q + kk) * OUT_C + c];
#pragma unroll
            for (int j = 0; j < MM2_NPW; ++j) {
                float xs = (kk == 0) ? xv[j].x : (kk == 1) ? xv[j].y : (kk == 2) ? xv[j].z : xv[j].w;
                acc[j] = fmaf(xs, wv, acc[j]);
            }
        }
    }
#pragma unroll
    for (int j = 0; j < MM2_NPW; ++j) {
        int n = n0 + 2 * j + half;
        xw2s[(size_t)n * OUT_C + c] = acc[j] * dis[n];
    }
}

// layer-2 aggregation: 32-lane group per node; dis folded; 4 gather loads in flight.
__global__ __launch_bounds__(256) void k_agg2(const float* __restrict__ xw2s, const int* __restrict__ csr_src,
                                              const int* __restrict__ row_ptr, const int* __restrict__ deg,
                                              const float* __restrict__ dis, const float* __restrict__ b2,
                                              float* __restrict__ out2) {
    int lane = threadIdx.x & 31;
    int v = blockIdx.x * 8 + (threadIdx.x >> 5);
    int start = row_ptr[v];
    int cnt = deg[v];
    float acc0 = xw2s[(size_t)v * OUT_C + lane];   // self-loop term
    float acc1 = 0.f;
    for (int base = 0; base < cnt; base += 32) {
        int mcnt = min(32, cnt - base);
        int sj = 0;
        if (lane < mcnt) sj = csr_src[start + base + lane];
        int j = 0;
        for (; j + 4 <= mcnt; j += 4) {
            int s0 = __shfl(sj, j + 0, 32), s1 = __shfl(sj, j + 1, 32);
            int s2 = __shfl(sj, j + 2, 32), s3 = __shfl(sj, j + 3, 32);
            float v0 = xw2s[(size_t)s0 * OUT_C + lane];
            float v1 = xw2s[(size_t)s1 * OUT_C + lane];
            float v2 = xw2s[(size_t)s2 * OUT_C + lane];
            float v3 = xw2s[(size_t)s3 * OUT_C + lane];
            acc0 += v0 + v2;
            acc1 += v1 + v3;
        }
        for (; j < mcnt; ++j) {
            int s = __shfl(sj, j, 32);
            acc0 += xw2s[(size_t)s * OUT_C + lane];
        }
    }
    out2[(size_t)v * OUT_C + lane] = fmaf(dis[v], acc0 + acc1, b2[lane]);
}

// per-graph top-30 by channel 31 (desc, stable), emit [512, 30*32] f32.
__global__ __launch_bounds__(256) void k_sort(const float* __restrict__ out2, float* __restrict__ out) {
    __shared__ float keys[NPG];
    __shared__ int order[TOPK];
    int g = blockIdx.x;
    int tid = threadIdx.x;
    int base = g * NPG;
    if (tid < NPG) keys[tid] = out2[(size_t)(base + tid) * OUT_C + (OUT_C - 1)];
    __syncthreads();
    if (tid < NPG) {
        float my = keys[tid];
        int r = 0;
        for (int j = 0; j < NPG; ++j) {
            float kj = keys[j];
            r += (kj > my) || (kj == my && j < tid);
        }
        if (r < TOPK) order[r] = tid;
    }
    __syncthreads();
    for (int idx = tid; idx < TOPK * OUT_C; idx += 256) {
        int r = idx >> 5;
        int c = idx & 31;
        int n = order[r];
        out[g * (TOPK * OUT_C) + idx] = out2[(size_t)(base + n) * OUT_C + c];
    }
}

extern "C" void kernel_launch(void* const* d_in, const int* in_sizes, int n_in,
                              void* d_out, int out_size, void* d_ws, size_t ws_size,
                              hipStream_t stream) {
    const float* x  = (const float*)d_in[0];
    const int*   ei = (const int*)d_in[1];
    const int*   srcp = ei;             // edge_index[0]
    const int*   dstp = ei + N_EDGES;   // edge_index[1]
    // d_in[2] (batch) unused: graphs are contiguous 196-node blocks.
    const float* W1 = (const float*)d_in[3];
    const float* b1 = (const float*)d_in[4];
    const float* W2 = (const float*)d_in[5];
    const float* b2 = (const float*)d_in[6];
    float* out = (float*)d_out;

    char* w = (char*)d_ws;
    int*    deg      = (int*)(w + OFF_DEG);
    int*    row_ptr  = (int*)(w + OFF_ROWPTR);
    int*    fill_pos = (int*)(w + OFF_FILL);
    int*    bsum     = (int*)(w + OFF_BSUM);
    int*    boff     = (int*)(w + OFF_BOFF);
    float*  dis      = (float*)(w + OFF_DIS);
    int*    csr_src  = (int*)(w + OFF_CSR);
    float*  xw1s     = (float*)(w + OFF_XW1);
    float*  h        = (float*)(w + OFF_H);
    float*  xw2s     = (float*)(w + OFF_XW2);
    float*  out2     = (float*)(w + OFF_OUT2);

    hipMemsetAsync(deg, 0, N_NODES * sizeof(int), stream);
    k_deg  <<<(N_EDGES + 255) / 256, 256, 0, stream>>>(dstp, deg);
    k_bsum <<<98, 1024, 0, stream>>>(deg, bsum);
    k_bscan<<<1, 64, 0, stream>>>(bsum, boff);
    k_scan <<<98, 1024, 0, stream>>>(deg, boff, row_ptr, fill_pos, dis);
    k_fill <<<(N_EDGES + 255) / 256, 256, 0, stream>>>(srcp, dstp, fill_pos, csr_src);
    k_mm1  <<<N_NODES / (MM1_NPW * 4), 256, 0, stream>>>(x, W1, dis, xw1s);
    k_agg1 <<<N_NODES / 4, 256, 0, stream>>>(xw1s, csr_src, row_ptr, deg, dis, b1, h);
    k_mm2  <<<N_NODES / (MM2_NPW * 2 * 4), 256, 0, stream>>>(h, W2, dis, xw2s);
    k_agg2 <<<N_NODES / 8, 256, 0, stream>>>(xw2s, csr_src, row_ptr, deg, dis, b2, out2);
    k_sort <<<NUM_GRAPHS, 256, 0, stream>>>(out2, out);
}